// Round 1
// baseline (346.030 us; speedup 1.0000x reference)
//
#include <hip/hip_runtime.h>

// QuaternionLinear as GEMM: M=32768 (batch), N=1024 (OUT_F*4), K=1024 (IN_F*4).
// W_eff[4o+r][4i+c] = sign(r,c) * weight[o][i][r^c], built in d_ws as bf16.
// GEMM: 128x128x64 tiles, 4 waves, mfma_f32_16x16x32_bf16, global_load_lds for B,
// fused fp32->bf16 conversion while staging A.

typedef __bf16 bf16x8_t __attribute__((ext_vector_type(8)));
typedef short short8    __attribute__((ext_vector_type(8)));
typedef float f32x4     __attribute__((ext_vector_type(4)));
typedef float f32x8     __attribute__((ext_vector_type(8)));

typedef const unsigned int __attribute__((address_space(1)))* gas_uint_ptr;
typedef unsigned int __attribute__((address_space(3)))*       las_uint_ptr;

// ---------------------------------------------------------------------------
// Prep: build effective bf16 weight matrix W_eff (1024 x 1024), row n = 4o+r,
// col k = 4i+c.  Component select s = r^c; sign packed as nibbles (r3..r0) =
// 0x2 0x8 0x4 0xE -> 0x284E, bit (r*4+c) set => negate.
// ---------------------------------------------------------------------------
__global__ __launch_bounds__(256) void build_weff(const float* __restrict__ w,
                                                  unsigned short* __restrict__ wq) {
    int idx = blockIdx.x * 256 + threadIdx.x;   // 0 .. 1048575
    int n = idx >> 10, k = idx & 1023;
    int o = n >> 2, r = n & 3, i = k >> 2, c = k & 3;
    int s = r ^ c;
    float v = w[o * 1024 + i * 4 + s];
    if ((0x284E >> (r * 4 + c)) & 1) v = -v;
    __bf16 b = (__bf16)v;
    union { __bf16 b; unsigned short u; } cv;
    cv.b = b;
    wq[idx] = cv.u;
}

// ---------------------------------------------------------------------------
// GEMM kernel. Grid = 2048 blocks: mtile = bid>>3 (256), ntile = bid&7 (8).
// ---------------------------------------------------------------------------
__global__ __launch_bounds__(256) void qlin_gemm(const float* __restrict__ X,
                                                 const unsigned short* __restrict__ Wq,
                                                 const float* __restrict__ bias,
                                                 float* __restrict__ out) {
    // Row-major tiles, row = 64 bf16 = 128 B (m97 layout, no padding so that
    // global_load_lds's wave-uniform-base + lane*16 rule is satisfied).
    __shared__ __align__(16) unsigned short As[128 * 64];   // 16 KiB
    __shared__ __align__(16) unsigned short Bs[128 * 64];   // 16 KiB

    const int t    = threadIdx.x;
    const int w    = t >> 6;
    const int l    = t & 63;
    const int lo16 = l & 15;
    const int hi2  = l >> 4;
    const int m0   = (blockIdx.x >> 3) * 128;
    const int n0   = (blockIdx.x & 7) * 128;
    const int wm   = (w & 1) * 64;
    const int wn   = (w >> 1) * 64;

    f32x4 acc[4][4] = {};

    for (int kt = 0; kt < 16; ++kt) {
        const int k0 = kt * 64;
        __syncthreads();   // protect LDS being re-filled from prior iter reads

        // --- B tile: W_eff bf16, async direct-to-LDS, 16 B per lane.
        // chunk c16 in [0,1024): LDS bytes [c16*16, +16), row = c16>>3,
        // k-offset = (c16&7)*8 bf16. Lanes of a wave are contiguous in c16 ->
        // contiguous LDS, satisfying the uniform-base+lane*16 constraint.
#pragma unroll
        for (int jj = 0; jj < 4; ++jj) {
            const int c16  = jj * 256 + t;
            const int row  = c16 >> 3;
            const int kcol = (c16 & 7) * 8;
            const unsigned short* gp = Wq + (n0 + row) * 1024 + k0 + kcol;
            __builtin_amdgcn_global_load_lds((gas_uint_ptr)gp,
                                             (las_uint_ptr)(Bs + c16 * 8),
                                             16, 0, 0);
        }

        // --- A tile: x fp32 -> bf16 fused conversion. 8 floats (32 B global)
        // -> 8 bf16 (16 B LDS) per chunk; v_cvt_pk_bf16_f32 via convertvector.
#pragma unroll
        for (int jj = 0; jj < 4; ++jj) {
            const int c16  = jj * 256 + t;
            const int row  = c16 >> 3;
            const int kcol = (c16 & 7) * 8;
            const float* gp = X + (m0 + row) * 1024 + k0 + kcol;
            f32x4 lo = *(const f32x4*)gp;
            f32x4 hi = *(const f32x4*)(gp + 4);
            f32x8 f8 = __builtin_shufflevector(lo, hi, 0, 1, 2, 3, 4, 5, 6, 7);
            bf16x8_t bv = __builtin_convertvector(f8, bf16x8_t);
            union { bf16x8_t b; short8 s; } cv;
            cv.b = bv;
            *(short8*)(As + c16 * 8) = cv.s;
        }

        __syncthreads();   // drains vmcnt (global_load_lds) + lgkmcnt (ds_write)

        // --- Compute: 2 k-steps of 32, 4x4 MFMA tiles per wave.
#pragma unroll
        for (int ks = 0; ks < 2; ++ks) {
            short8 af[4], bf[4];
#pragma unroll
            for (int mt = 0; mt < 4; ++mt)
                af[mt] = *(const short8*)(As + (wm + mt * 16 + lo16) * 64 + ks * 32 + hi2 * 8);
#pragma unroll
            for (int nt = 0; nt < 4; ++nt)
                bf[nt] = *(const short8*)(Bs + (wn + nt * 16 + lo16) * 64 + ks * 32 + hi2 * 8);
#pragma unroll
            for (int mt = 0; mt < 4; ++mt)
#pragma unroll
                for (int nt = 0; nt < 4; ++nt)
                    acc[mt][nt] = __builtin_amdgcn_mfma_f32_16x16x32_bf16(
                        af[mt], bf[nt], acc[mt][nt], 0, 0, 0);
        }
    }

    // --- Epilogue: C/D layout col(n) = lane&15, row(m) = (lane>>4)*4 + reg.
#pragma unroll
    for (int nt = 0; nt < 4; ++nt) {
        const int n  = n0 + wn + nt * 16 + lo16;
        const float bv = bias[n];
#pragma unroll
        for (int mt = 0; mt < 4; ++mt) {
            const int mb = m0 + wm + mt * 16 + hi2 * 4;
#pragma unroll
            for (int r = 0; r < 4; ++r)
                out[(mb + r) * 1024 + n] = acc[mt][nt][r] + bv;
        }
    }
}

// ---------------------------------------------------------------------------
extern "C" void kernel_launch(void* const* d_in, const int* in_sizes, int n_in,
                              void* d_out, int out_size, void* d_ws, size_t ws_size,
                              hipStream_t stream) {
    const float* x  = (const float*)d_in[0];   // (32768, 256, 4) fp32
    const float* wt = (const float*)d_in[1];   // (256, 256, 4) fp32
    const float* bs = (const float*)d_in[2];   // (256, 4) fp32
    float* out = (float*)d_out;                // (32768, 256, 4) fp32
    unsigned short* wq = (unsigned short*)d_ws; // 1024*1024 bf16 = 2 MiB scratch

    build_weff<<<4096, 256, 0, stream>>>(wt, wq);
    qlin_gemm<<<2048, 256, 0, stream>>>(x, wq, bs, out);

    (void)in_sizes; (void)n_in; (void)out_size; (void)ws_size;
}

// Round 2
// 340.170 us; speedup vs baseline: 1.0172x; 1.0172x over previous
//
#include <hip/hip_runtime.h>

// QuaternionLinear as GEMM: M=32768 (batch), N=1024 (OUT_F*4), K=1024 (IN_F*4).
// W_eff[4o+r][4i+c] = sign(r,c) * weight[o][i][r^c], built in d_ws as bf16.
// GEMM: 128x128x64 tiles, 4 waves, mfma_f32_16x16x32_bf16, global_load_lds for B,
// fused fp32->bf16 conversion while staging A.
//
// R2: (a) XCD-aware grid swizzle — the 8 n-tiles of one m-stripe co-reside on
// one XCD so its L2 captures the 8x A-reuse (R1 FETCH_SIZE showed 4x over-fetch).
// (b) XOR bank swizzle of the LDS tile layout — R1 fragment reads were 16-way
// bank-conflicted (row stride 128 B); chunk position p = row*8 + (g ^ (row&7))
// spreads the 16 lanes across 8 bank groups (2-way = free). global_load_lds's
// lane-contiguous-destination rule is kept by permuting the SOURCE address.

typedef __bf16 bf16x8_t __attribute__((ext_vector_type(8)));
typedef short short8    __attribute__((ext_vector_type(8)));
typedef float f32x4     __attribute__((ext_vector_type(4)));
typedef float f32x8     __attribute__((ext_vector_type(8)));

typedef const unsigned int __attribute__((address_space(1)))* gas_uint_ptr;
typedef unsigned int __attribute__((address_space(3)))*       las_uint_ptr;

// ---------------------------------------------------------------------------
// Prep: build effective bf16 weight matrix W_eff (1024 x 1024), row n = 4o+r,
// col k = 4i+c.  Component select s = r^c; sign bit from table 0x284E.
// ---------------------------------------------------------------------------
__global__ __launch_bounds__(256) void build_weff(const float* __restrict__ w,
                                                  unsigned short* __restrict__ wq) {
    int idx = blockIdx.x * 256 + threadIdx.x;   // 0 .. 1048575
    int n = idx >> 10, k = idx & 1023;
    int o = n >> 2, r = n & 3, i = k >> 2, c = k & 3;
    int s = r ^ c;
    float v = w[o * 1024 + i * 4 + s];
    if ((0x284E >> (r * 4 + c)) & 1) v = -v;
    __bf16 b = (__bf16)v;
    union { __bf16 b; unsigned short u; } cv;
    cv.b = b;
    wq[idx] = cv.u;
}

// ---------------------------------------------------------------------------
// GEMM kernel. Grid = 2048 blocks.
// XCD swizzle: xcd = bid&7 (HW round-robin), m-tile = xcd*32 + (s>>3), n = s&7.
// ---------------------------------------------------------------------------
__global__ __launch_bounds__(256) void qlin_gemm(const float* __restrict__ X,
                                                 const unsigned short* __restrict__ Wq,
                                                 const float* __restrict__ bias,
                                                 float* __restrict__ out) {
    // Tiles stored as 1024 chunks of 16 B (8 bf16). Logical (row r, chunk g)
    // lives at position p = r*8 + (g ^ (r&7))  — XOR bank swizzle.
    __shared__ __align__(16) unsigned short As[128 * 64];   // 16 KiB
    __shared__ __align__(16) unsigned short Bs[128 * 64];   // 16 KiB

    const int t    = threadIdx.x;
    const int w    = t >> 6;
    const int l    = t & 63;
    const int lo16 = l & 15;
    const int hi2  = l >> 4;

    const int bid  = blockIdx.x;
    const int xcd  = bid & 7;
    const int s    = bid >> 3;              // 0..255 within this XCD
    const int m0   = (xcd * 32 + (s >> 3)) * 128;
    const int n0   = (s & 7) * 128;

    const int wm   = (w & 1) * 64;
    const int wn   = (w >> 1) * 64;

    f32x4 acc[4][4] = {};

    for (int kt = 0; kt < 16; ++kt) {
        const int k0 = kt * 64;
        __syncthreads();   // protect LDS being re-filled from prior iter reads

        // --- B tile: async direct-to-LDS, 16 B per lane. LDS position p = c16
        // is lane-contiguous (required); the global SOURCE chunk is the one
        // that belongs at swizzled position p: row = p>>3, g = (p&7)^(row&7).
#pragma unroll
        for (int jj = 0; jj < 4; ++jj) {
            const int p    = jj * 256 + t;
            const int row  = p >> 3;
            const int g    = (p & 7) ^ (row & 7);
            const unsigned short* gp = Wq + (n0 + row) * 1024 + k0 + g * 8;
            __builtin_amdgcn_global_load_lds((gas_uint_ptr)gp,
                                             (las_uint_ptr)(Bs + p * 8),
                                             16, 0, 0);
        }

        // --- A tile: fp32 -> bf16 fused conversion; global read stays fully
        // coalesced (row,g natural order), LDS write goes to swizzled p.
#pragma unroll
        for (int jj = 0; jj < 4; ++jj) {
            const int c    = jj * 256 + t;
            const int row  = c >> 3;
            const int g    = c & 7;
            const float* gp = X + (m0 + row) * 1024 + k0 + g * 8;
            f32x4 lo = *(const f32x4*)gp;
            f32x4 hi = *(const f32x4*)(gp + 4);
            f32x8 f8 = __builtin_shufflevector(lo, hi, 0, 1, 2, 3, 4, 5, 6, 7);
            bf16x8_t bv = __builtin_convertvector(f8, bf16x8_t);
            union { bf16x8_t b; short8 s; } cv;
            cv.b = bv;
            const int p = row * 8 + (g ^ (row & 7));
            *(short8*)(As + p * 8) = cv.s;
        }

        __syncthreads();   // drains vmcnt (global_load_lds) + lgkmcnt (ds_write)

        // --- Compute: 2 k-steps of 32, 4x4 MFMA tiles per wave.
#pragma unroll
        for (int ks = 0; ks < 2; ++ks) {
            const int g = ks * 4 + hi2;     // chunk index within row
            short8 af[4], bf[4];
#pragma unroll
            for (int mt = 0; mt < 4; ++mt) {
                const int r = wm + mt * 16 + lo16;
                af[mt] = *(const short8*)(As + (r * 8 + (g ^ (r & 7))) * 8);
            }
#pragma unroll
            for (int nt = 0; nt < 4; ++nt) {
                const int r = wn + nt * 16 + lo16;
                bf[nt] = *(const short8*)(Bs + (r * 8 + (g ^ (r & 7))) * 8);
            }
#pragma unroll
            for (int mt = 0; mt < 4; ++mt)
#pragma unroll
                for (int nt = 0; nt < 4; ++nt)
                    acc[mt][nt] = __builtin_amdgcn_mfma_f32_16x16x32_bf16(
                        af[mt], bf[nt], acc[mt][nt], 0, 0, 0);
        }
    }

    // --- Epilogue: C/D layout col(n) = lane&15, row(m) = (lane>>4)*4 + reg.
#pragma unroll
    for (int nt = 0; nt < 4; ++nt) {
        const int n  = n0 + wn + nt * 16 + lo16;
        const float bv = bias[n];
#pragma unroll
        for (int mt = 0; mt < 4; ++mt) {
            const int mb = m0 + wm + mt * 16 + hi2 * 4;
#pragma unroll
            for (int r = 0; r < 4; ++r)
                out[(mb + r) * 1024 + n] = acc[mt][nt][r] + bv;
        }
    }
}

// ---------------------------------------------------------------------------
extern "C" void kernel_launch(void* const* d_in, const int* in_sizes, int n_in,
                              void* d_out, int out_size, void* d_ws, size_t ws_size,
                              hipStream_t stream) {
    const float* x  = (const float*)d_in[0];   // (32768, 256, 4) fp32
    const float* wt = (const float*)d_in[1];   // (256, 256, 4) fp32
    const float* bs = (const float*)d_in[2];   // (256, 4) fp32
    float* out = (float*)d_out;                // (32768, 256, 4) fp32
    unsigned short* wq = (unsigned short*)d_ws; // 1024*1024 bf16 = 2 MiB scratch

    build_weff<<<4096, 256, 0, stream>>>(wt, wq);
    qlin_gemm<<<2048, 256, 0, stream>>>(x, wq, bs, out);

    (void)in_sizes; (void)n_in; (void)out_size; (void)ws_size;
}

// Round 3
// 308.341 us; speedup vs baseline: 1.1222x; 1.1032x over previous
//
#include <hip/hip_runtime.h>

// QuaternionLinear as GEMM: M=32768 (batch), N=1024 (OUT_F*4), K=1024 (IN_F*4).
// W_eff[4o+r][4i+c] = sign(r,c) * weight[o][i][r^c], built in d_ws as bf16.
//
// R3: R2's counters showed latency-bound (MfmaUtil 15%, HBM 16%, all pipes
// idle) — the fp32 A-path (global_load -> vmcnt wait -> cvt -> ds_write)
// exposed ~900cyc HBM latency inside every K-iter. Fix: pre-convert x to bf16
// in a separate streaming pass (pure BW-bound, ~33us), then the GEMM is pure
// m97 structure: BOTH operands staged with global_load_lds width=16 (latency
// drained once at the barrier, overlapped across resident waves).
// Keeps R2's XCD-aware grid swizzle (FETCH 528->99MB) and XOR bank swizzle
// (LDS conflicts 2.5e7->0).
// Fallback: if ws_size < 2MiB + 64MiB, use the R2 fused-conversion GEMM.

typedef __bf16 bf16x8_t __attribute__((ext_vector_type(8)));
typedef short short8    __attribute__((ext_vector_type(8)));
typedef float f32x4     __attribute__((ext_vector_type(4)));
typedef float f32x8     __attribute__((ext_vector_type(8)));

typedef const unsigned int __attribute__((address_space(1)))* gas_uint_ptr;
typedef unsigned int __attribute__((address_space(3)))*       las_uint_ptr;

// ---------------------------------------------------------------------------
// Prep: build effective bf16 weight matrix W_eff (1024 x 1024), row n = 4o+r,
// col k = 4i+c.  Component select s = r^c; sign bit from table 0x284E.
// ---------------------------------------------------------------------------
__global__ __launch_bounds__(256) void build_weff(const float* __restrict__ w,
                                                  unsigned short* __restrict__ wq) {
    int idx = blockIdx.x * 256 + threadIdx.x;   // 0 .. 1048575
    int n = idx >> 10, k = idx & 1023;
    int o = n >> 2, r = n & 3, i = k >> 2, c = k & 3;
    int s = r ^ c;
    float v = w[o * 1024 + i * 4 + s];
    if ((0x284E >> (r * 4 + c)) & 1) v = -v;
    union { __bf16 b; unsigned short u; } cv;
    cv.b = (__bf16)v;
    wq[idx] = cv.u;
}

// ---------------------------------------------------------------------------
// Streaming fp32 -> bf16 conversion of x (33.5M elements). Pure BW-bound.
// ---------------------------------------------------------------------------
__global__ __launch_bounds__(256) void conv_x(const float* __restrict__ x,
                                              unsigned short* __restrict__ xb) {
    const long long c = (long long)blockIdx.x * 256 + threadIdx.x; // 8-elem chunk
    const float* gp = x + c * 8;
    f32x4 lo = *(const f32x4*)gp;
    f32x4 hi = *(const f32x4*)(gp + 4);
    f32x8 f8 = __builtin_shufflevector(lo, hi, 0, 1, 2, 3, 4, 5, 6, 7);
    bf16x8_t bv = __builtin_convertvector(f8, bf16x8_t);
    union { bf16x8_t b; short8 s; } cv;
    cv.b = bv;
    *(short8*)(xb + c * 8) = cv.s;
}

// ---------------------------------------------------------------------------
// GEMM, m97 structure: both tiles via global_load_lds. Grid = 2048 blocks.
// XCD swizzle: xcd = bid&7 (HW round-robin), m-tile = xcd*32 + (s>>3), n = s&7.
// LDS tiles stored as 1024 chunks of 16 B; logical (row r, chunk g) lives at
// position p = r*8 + (g ^ (r&7)) — XOR bank swizzle (conflict-free, verified
// R2: SQ_LDS_BANK_CONFLICT = 0). global_load_lds destination is lane-
// contiguous in p; the SOURCE address is permuted instead.
// ---------------------------------------------------------------------------
__global__ __launch_bounds__(256) void qlin_gemm_bf(const unsigned short* __restrict__ Xb,
                                                    const unsigned short* __restrict__ Wq,
                                                    const float* __restrict__ bias,
                                                    float* __restrict__ out) {
    __shared__ __align__(16) unsigned short As[128 * 64];   // 16 KiB
    __shared__ __align__(16) unsigned short Bs[128 * 64];   // 16 KiB

    const int t    = threadIdx.x;
    const int w    = t >> 6;
    const int l    = t & 63;
    const int lo16 = l & 15;
    const int hi2  = l >> 4;

    const int bid  = blockIdx.x;
    const int xcd  = bid & 7;
    const int s    = bid >> 3;              // 0..255 within this XCD
    const int m0   = (xcd * 32 + (s >> 3)) * 128;
    const int n0   = (s & 7) * 128;

    const int wm   = (w & 1) * 64;
    const int wn   = (w >> 1) * 64;

    f32x4 acc[4][4] = {};

    for (int kt = 0; kt < 16; ++kt) {
        const int k0 = kt * 64;
        __syncthreads();   // protect LDS being re-filled from prior iter reads

#pragma unroll
        for (int jj = 0; jj < 4; ++jj) {
            const int p    = jj * 256 + t;
            const int row  = p >> 3;
            const int g    = (p & 7) ^ (row & 7);
            const unsigned short* ga = Xb + (long long)(m0 + row) * 1024 + k0 + g * 8;
            const unsigned short* gb = Wq + (n0 + row) * 1024 + k0 + g * 8;
            __builtin_amdgcn_global_load_lds((gas_uint_ptr)ga,
                                             (las_uint_ptr)(As + p * 8), 16, 0, 0);
            __builtin_amdgcn_global_load_lds((gas_uint_ptr)gb,
                                             (las_uint_ptr)(Bs + p * 8), 16, 0, 0);
        }

        __syncthreads();   // drains vmcnt (global_load_lds)

#pragma unroll
        for (int ks = 0; ks < 2; ++ks) {
            const int g = ks * 4 + hi2;     // chunk index within row
            short8 af[4], bf[4];
#pragma unroll
            for (int mt = 0; mt < 4; ++mt) {
                const int r = wm + mt * 16 + lo16;
                af[mt] = *(const short8*)(As + (r * 8 + (g ^ (r & 7))) * 8);
            }
#pragma unroll
            for (int nt = 0; nt < 4; ++nt) {
                const int r = wn + nt * 16 + lo16;
                bf[nt] = *(const short8*)(Bs + (r * 8 + (g ^ (r & 7))) * 8);
            }
#pragma unroll
            for (int mt = 0; mt < 4; ++mt)
#pragma unroll
                for (int nt = 0; nt < 4; ++nt)
                    acc[mt][nt] = __builtin_amdgcn_mfma_f32_16x16x32_bf16(
                        af[mt], bf[nt], acc[mt][nt], 0, 0, 0);
        }
    }

    // Epilogue: C/D layout col(n) = lane&15, row(m) = (lane>>4)*4 + reg.
#pragma unroll
    for (int nt = 0; nt < 4; ++nt) {
        const int n  = n0 + wn + nt * 16 + lo16;
        const float bv = bias[n];
#pragma unroll
        for (int mt = 0; mt < 4; ++mt) {
            const int mb = m0 + wm + mt * 16 + hi2 * 4;
#pragma unroll
            for (int r = 0; r < 4; ++r)
                out[(long long)(mb + r) * 1024 + n] = acc[mt][nt][r] + bv;
        }
    }
}

// ---------------------------------------------------------------------------
// Fallback GEMM (R2): fused fp32->bf16 A staging. Used only if ws too small.
// ---------------------------------------------------------------------------
__global__ __launch_bounds__(256) void qlin_gemm_fused(const float* __restrict__ X,
                                                       const unsigned short* __restrict__ Wq,
                                                       const float* __restrict__ bias,
                                                       float* __restrict__ out) {
    __shared__ __align__(16) unsigned short As[128 * 64];
    __shared__ __align__(16) unsigned short Bs[128 * 64];

    const int t    = threadIdx.x;
    const int w    = t >> 6;
    const int l    = t & 63;
    const int lo16 = l & 15;
    const int hi2  = l >> 4;
    const int bid  = blockIdx.x;
    const int xcd  = bid & 7;
    const int s    = bid >> 3;
    const int m0   = (xcd * 32 + (s >> 3)) * 128;
    const int n0   = (s & 7) * 128;
    const int wm   = (w & 1) * 64;
    const int wn   = (w >> 1) * 64;

    f32x4 acc[4][4] = {};

    for (int kt = 0; kt < 16; ++kt) {
        const int k0 = kt * 64;
        __syncthreads();
#pragma unroll
        for (int jj = 0; jj < 4; ++jj) {
            const int p    = jj * 256 + t;
            const int row  = p >> 3;
            const int g    = (p & 7) ^ (row & 7);
            const unsigned short* gp = Wq + (n0 + row) * 1024 + k0 + g * 8;
            __builtin_amdgcn_global_load_lds((gas_uint_ptr)gp,
                                             (las_uint_ptr)(Bs + p * 8), 16, 0, 0);
        }
#pragma unroll
        for (int jj = 0; jj < 4; ++jj) {
            const int c    = jj * 256 + t;
            const int row  = c >> 3;
            const int g    = c & 7;
            const float* gp = X + (long long)(m0 + row) * 1024 + k0 + g * 8;
            f32x4 lo = *(const f32x4*)gp;
            f32x4 hi = *(const f32x4*)(gp + 4);
            f32x8 f8 = __builtin_shufflevector(lo, hi, 0, 1, 2, 3, 4, 5, 6, 7);
            bf16x8_t bv = __builtin_convertvector(f8, bf16x8_t);
            union { bf16x8_t b; short8 s; } cv;
            cv.b = bv;
            const int p = row * 8 + (g ^ (row & 7));
            *(short8*)(As + p * 8) = cv.s;
        }
        __syncthreads();
#pragma unroll
        for (int ks = 0; ks < 2; ++ks) {
            const int g = ks * 4 + hi2;
            short8 af[4], bf[4];
#pragma unroll
            for (int mt = 0; mt < 4; ++mt) {
                const int r = wm + mt * 16 + lo16;
                af[mt] = *(const short8*)(As + (r * 8 + (g ^ (r & 7))) * 8);
            }
#pragma unroll
            for (int nt = 0; nt < 4; ++nt) {
                const int r = wn + nt * 16 + lo16;
                bf[nt] = *(const short8*)(Bs + (r * 8 + (g ^ (r & 7))) * 8);
            }
#pragma unroll
            for (int mt = 0; mt < 4; ++mt)
#pragma unroll
                for (int nt = 0; nt < 4; ++nt)
                    acc[mt][nt] = __builtin_amdgcn_mfma_f32_16x16x32_bf16(
                        af[mt], bf[nt], acc[mt][nt], 0, 0, 0);
        }
    }

#pragma unroll
    for (int nt = 0; nt < 4; ++nt) {
        const int n  = n0 + wn + nt * 16 + lo16;
        const float bv = bias[n];
#pragma unroll
        for (int mt = 0; mt < 4; ++mt) {
            const int mb = m0 + wm + mt * 16 + hi2 * 4;
#pragma unroll
            for (int r = 0; r < 4; ++r)
                out[(long long)(mb + r) * 1024 + n] = acc[mt][nt][r] + bv;
        }
    }
}

// ---------------------------------------------------------------------------
extern "C" void kernel_launch(void* const* d_in, const int* in_sizes, int n_in,
                              void* d_out, int out_size, void* d_ws, size_t ws_size,
                              hipStream_t stream) {
    const float* x  = (const float*)d_in[0];   // (32768, 256, 4) fp32
    const float* wt = (const float*)d_in[1];   // (256, 256, 4) fp32
    const float* bs = (const float*)d_in[2];   // (256, 4) fp32
    float* out = (float*)d_out;                // (32768, 256, 4) fp32

    unsigned short* wq = (unsigned short*)d_ws;            // 2 MiB W_eff bf16
    const size_t WQ_BYTES = 1024ull * 1024 * 2;
    const size_t XB_BYTES = 32768ull * 1024 * 2;           // 64 MiB x bf16

    build_weff<<<4096, 256, 0, stream>>>(wt, wq);

    if (ws_size >= WQ_BYTES + XB_BYTES) {
        unsigned short* xb = (unsigned short*)((char*)d_ws + WQ_BYTES);
        conv_x<<<16384, 256, 0, stream>>>(x, xb);          // 33.5M elems / 8
        qlin_gemm_bf<<<2048, 256, 0, stream>>>(xb, wq, bs, out);
    } else {
        qlin_gemm_fused<<<2048, 256, 0, stream>>>(x, wq, bs, out);
    }

    (void)in_sizes; (void)n_in; (void)out_size;
}